// Round 3
// baseline (100.793 us; speedup 1.0000x reference)
//
#include <hip/hip_runtime.h>
#include <math.h>

namespace {
constexpr int Bn = 8;
constexpr int Ln = 8192;
constexpr int Rn = 64;
constexpr int Hn = 512;
constexpr int LT = 128;
constexpr int NSEG = Ln / LT;            // 64 segments per batch
constexpr int NK1 = Bn * NSEG;           // 512 k1 blocks

// workspace float offsets
constexpr size_t PS        = 8352;       // per-k1-block partial stride
constexpr size_t OFF_G     = 0;                                   // 64x64
constexpr size_t OFF_W     = 4096;                                // 64
constexpr size_t OFF_BB    = 4160;                                // 1 (+pad)
constexpr size_t OFF_STATS = 4224;                                // NK1 * PS
constexpr size_t OFF_A1R   = OFF_STATS + (size_t)NK1 * PS;        // B*4096
constexpr size_t OFF_A2R   = OFF_A1R + (size_t)Bn * 4096;         // B*4096
constexpr size_t OFF_U1R   = OFF_A2R + (size_t)Bn * 4096;         // B*64
constexpr size_t OFF_U2R   = OFF_U1R + (size_t)Bn * 64;           // B*64
constexpr size_t OFF_SIG   = OFF_U2R + (size_t)Bn * 64;           // B*2 (pad 64)
constexpr size_t OFF_M     = OFF_SIG + 64;                        // B*64*H  (M = Wk C)
constexpr size_t OFF_C1    = OFF_M + (size_t)Bn * 64 * Hn;        // B*H     (c1 = bk^T C)
constexpr size_t OFF_TD    = OFF_C1 + (size_t)Bn * Hn;            // B*64*H
constexpr size_t OFF_P1    = OFF_TD + (size_t)Bn * 64 * Hn;       // B*H
constexpr size_t OFF_P2    = OFF_P1 + (size_t)Bn * Hn;            // B*H
constexpr size_t OFF_Q1    = OFF_P2 + (size_t)Bn * Hn;            // B*H
constexpr size_t OFF_GV    = OFF_Q1 + (size_t)Bn * Hn;            // B*H     (g = u2^T M)
}

// ---------------------------------------------------------------------------
// kA: blocks 0..15: G = Wk*Wk^T; block 16: w = Wk*bk, bb = bk.bk
//     blocks 17..144: M = Wk @ C (per batch, 32-wide d strips, full h), c1 = bk^T C
// grid 145 x 256
__global__ __launch_bounds__(256) void kA_pre(const float* __restrict__ Wk,
                                              const float* __restrict__ bk,
                                              const float* __restrict__ C,
                                              float* __restrict__ ws) {
  const int t = threadIdx.x;
  const int blk = blockIdx.x;
  if (blk < 16) {
    const int e = blk * 256 + t;
    const int i = e >> 6, j = e & 63;
    const float4* a4 = (const float4*)(Wk + (size_t)i * Hn);
    const float4* b4 = (const float4*)(Wk + (size_t)j * Hn);
    float s0 = 0.f, s1 = 0.f, s2 = 0.f, s3 = 0.f;
    for (int h = 0; h < Hn / 4; ++h) {
      float4 x = a4[h], y = b4[h];
      s0 += x.x * y.x; s1 += x.y * y.y; s2 += x.z * y.z; s3 += x.w * y.w;
    }
    ws[OFF_G + e] = (s0 + s1) + (s2 + s3);
    return;
  }
  if (blk == 16) {
    if (t < 64) {
      float s = 0.f;
      for (int h = 0; h < Hn; ++h) s += Wk[(size_t)t * Hn + h] * bk[h];
      ws[OFF_W + t] = s;
    } else if (t == 64) {
      float s = 0.f;
      for (int h = 0; h < Hn; ++h) s += bk[h] * bk[h];
      ws[OFF_BB] = s;
    }
    return;
  }

  // ---- M / c1 part ----
  __shared__ __align__(16) float Cs[64][36];   // [h within tile][d within strip]
  __shared__ __align__(16) float Wks[64][66];  // [i][h within tile]
  __shared__ __align__(16) float bks[64];

  const int m = blk - 17;
  const int b = m >> 4;
  const int ds = m & 15;
  const int d04 = ds * 8;                      // float4 offset of 32-wide d strip
  const float4* C4b = (const float4*)(C + (size_t)b * Hn * Hn);
  const float4* Wk4 = (const float4*)Wk;

  const int ig = t >> 3;                       // 0..31, rows i = ig*2, ig*2+1
  const int tj4 = t & 7;                       // float4 col in strip

  float4 acc0 = make_float4(0.f, 0.f, 0.f, 0.f);
  float4 acc1 = make_float4(0.f, 0.f, 0.f, 0.f);
  float4 c1a  = make_float4(0.f, 0.f, 0.f, 0.f);

  for (int ht = 0; ht < 8; ++ht) {
    const int h0 = ht * 64;
    #pragma unroll
    for (int p = 0; p < 2; ++p) {
      const int idx = p * 256 + t;             // 512 float4
      const int r = idx >> 3, c4 = idx & 7;
      *(float4*)&Cs[r][c4 * 4] = C4b[(size_t)(h0 + r) * 128 + d04 + c4];
    }
    #pragma unroll
    for (int p = 0; p < 4; ++p) {
      const int idx = p * 256 + t;             // 1024 float4
      const int r = idx >> 4, c4 = idx & 15;
      *(float4*)&Wks[r][c4 * 4] = Wk4[(size_t)r * 128 + (h0 >> 2) + c4];
    }
    if (t < 16) *(float4*)&bks[t * 4] = *(const float4*)&bk[h0 + t * 4];
    __syncthreads();

    #pragma unroll 8
    for (int hh = 0; hh < 64; ++hh) {
      const float4 cv = *(const float4*)&Cs[hh][tj4 * 4];
      const float w0 = Wks[ig * 2][hh];
      const float w1 = Wks[ig * 2 + 1][hh];
      acc0.x += w0 * cv.x; acc0.y += w0 * cv.y; acc0.z += w0 * cv.z; acc0.w += w0 * cv.w;
      acc1.x += w1 * cv.x; acc1.y += w1 * cv.y; acc1.z += w1 * cv.z; acc1.w += w1 * cv.w;
      if (ig == 0) {
        const float bkv = bks[hh];
        c1a.x += bkv * cv.x; c1a.y += bkv * cv.y; c1a.z += bkv * cv.z; c1a.w += bkv * cv.w;
      }
    }
    __syncthreads();
  }

  float4* M4 = (float4*)(ws + OFF_M);
  M4[(size_t)(b * 64 + ig * 2)     * 128 + d04 + tj4] = acc0;
  M4[(size_t)(b * 64 + ig * 2 + 1) * 128 + d04 + tj4] = acc1;
  if (ig == 0) {
    float4* c14 = (float4*)(ws + OFF_C1);
    c14[(size_t)b * 128 + d04 + tj4] = c1a;
  }
}

// ---------------------------------------------------------------------------
// k1: per 128-row tile: row norms via x*G*x + 2x.w + bb, then accumulate
//     A1 = X^T D X, A2 = X^T D^2 X, u1, u2, sig partials.
// grid 512 (= 8 b x 64 seg) x 256
__global__ __launch_bounds__(256) void k1_stats(const float* __restrict__ hs,
                                                float* __restrict__ ws) {
  __shared__ __align__(16) float XT[64][132];   // [r][l], padded
  __shared__ __align__(16) float Gs[64][64];
  __shared__ __align__(16) float wsh[64];
  __shared__ __align__(16) float n2p[8][LT];
  __shared__ __align__(16) float d1s[LT];
  __shared__ __align__(16) float d2s[LT];

  const int t = threadIdx.x;
  const int blk = blockIdx.x;
  const int b = blk >> 6;
  const int seg = blk & 63;

  for (int k = 0; k < 16; ++k) {
    int e = k * 256 + t;
    (&Gs[0][0])[e] = ws[OFF_G + e];
  }
  if (t < 64) wsh[t] = ws[OFF_W + t];
  const float bb = ws[OFF_BB];

  // stage X transposed: XT[r][l]
  {
    const float4* src = (const float4*)(hs + ((size_t)b * Ln + (size_t)seg * LT) * Rn);
    #pragma unroll
    for (int k = 0; k < 8; ++k) {
      int f = k * 256 + t;
      float4 v = src[f];
      int l = f >> 4, j0 = (f & 15) << 2;
      XT[j0 + 0][l] = v.x; XT[j0 + 1][l] = v.y; XT[j0 + 2][l] = v.z; XT[j0 + 3][l] = v.w;
    }
  }
  __syncthreads();

  // phase A: Y[i][l] = sum_k G[i][k]*XT[k][l]; n2 partials
  {
    const int i0 = (t & 7) * 8;
    const int la = (t >> 3) * 4;
    float acc[8][4] = {};
    for (int k = 0; k < 64; ++k) {
      const float4 g0 = *(const float4*)&Gs[k][i0];
      const float4 g1 = *(const float4*)&Gs[k][i0 + 4];
      const float4 xv = *(const float4*)&XT[k][la];
      const float ga[8] = {g0.x, g0.y, g0.z, g0.w, g1.x, g1.y, g1.z, g1.w};
      const float xa[4] = {xv.x, xv.y, xv.z, xv.w};
      #pragma unroll
      for (int a = 0; a < 8; ++a)
        #pragma unroll
        for (int lv = 0; lv < 4; ++lv)
          acc[a][lv] += ga[a] * xa[lv];
    }
    #pragma unroll
    for (int lv = 0; lv < 4; ++lv) {
      float s = 0.f;
      #pragma unroll
      for (int a = 0; a < 8; ++a)
        s += XT[i0 + a][la + lv] * (acc[a][lv] + 2.0f * wsh[i0 + a]);
      n2p[t & 7][la + lv] = s;
    }
  }
  __syncthreads();
  if (t < LT) {
    float n2 = bb;
    #pragma unroll
    for (int p = 0; p < 8; ++p) n2 += n2p[p][t];
    n2 = fmaxf(n2, 0.0f);
    const float d1 = 1.0f / fmaxf(sqrtf(n2), 1e-12f);
    d1s[t] = d1;
    d2s[t] = d1 * d1;
  }
  __syncthreads();

  float sg1 = 0.f, sg2 = 0.f;
  if (t < 64) {
    float a1 = d1s[t] + d1s[t + 64];
    float a2 = d2s[t] + d2s[t + 64];
    #pragma unroll
    for (int off = 32; off > 0; off >>= 1) {
      a1 += __shfl_down(a1, off, 64);
      a2 += __shfl_down(a2, off, 64);
    }
    sg1 = a1; sg2 = a2;
  }

  // phase B: A1/A2 4x4 per-thread accumulation over the tile
  const int bi0 = (t >> 4) * 4;
  const int bj0 = (t & 15) * 4;
  float A1a[4][4] = {}, A2a[4][4] = {};
  float u1a[4] = {0.f, 0.f, 0.f, 0.f}, u2a[4] = {0.f, 0.f, 0.f, 0.f};
  for (int l4 = 0; l4 < LT; l4 += 4) {
    const float4 q1 = *(const float4*)&d1s[l4];
    const float4 q2 = *(const float4*)&d2s[l4];
    const float d1v[4] = {q1.x, q1.y, q1.z, q1.w};
    const float d2v[4] = {q2.x, q2.y, q2.z, q2.w};
    float e1[4][4], e2[4][4], xj[4][4];
    #pragma unroll
    for (int a = 0; a < 4; ++a) {
      const float4 xv = *(const float4*)&XT[bi0 + a][l4];
      const float xa[4] = {xv.x, xv.y, xv.z, xv.w};
      #pragma unroll
      for (int lv = 0; lv < 4; ++lv) {
        e1[a][lv] = d1v[lv] * xa[lv];
        e2[a][lv] = d2v[lv] * xa[lv];
      }
    }
    #pragma unroll
    for (int bq = 0; bq < 4; ++bq) {
      const float4 xv = *(const float4*)&XT[bj0 + bq][l4];
      xj[bq][0] = xv.x; xj[bq][1] = xv.y; xj[bq][2] = xv.z; xj[bq][3] = xv.w;
    }
    #pragma unroll
    for (int a = 0; a < 4; ++a)
      #pragma unroll
      for (int bq = 0; bq < 4; ++bq) {
        float s1 = A1a[a][bq], s2 = A2a[a][bq];
        #pragma unroll
        for (int lv = 0; lv < 4; ++lv) {
          s1 += e1[a][lv] * xj[bq][lv];
          s2 += e2[a][lv] * xj[bq][lv];
        }
        A1a[a][bq] = s1; A2a[a][bq] = s2;
      }
    if (bj0 == 0) {
      #pragma unroll
      for (int a = 0; a < 4; ++a)
        #pragma unroll
        for (int lv = 0; lv < 4; ++lv) {
          u1a[a] += e1[a][lv];
          u2a[a] += e2[a][lv];
        }
    }
  }

  float* P = ws + OFF_STATS + (size_t)blk * PS;
  #pragma unroll
  for (int a = 0; a < 4; ++a)
    #pragma unroll
    for (int bq = 0; bq < 4; ++bq) {
      P[(bi0 + a) * 64 + bj0 + bq] = A1a[a][bq];
      P[4096 + (bi0 + a) * 64 + bj0 + bq] = A2a[a][bq];
    }
  if (bj0 == 0) {
    #pragma unroll
    for (int a = 0; a < 4; ++a) {
      P[8192 + bi0 + a] = u1a[a];
      P[8256 + bi0 + a] = u2a[a];
    }
  }
  if (t == 0) { P[8320] = sg1; P[8321] = sg2; }
}

// ---------------------------------------------------------------------------
// k1b: reduce 64 partials per batch -> A1R, A2R, U1R, U2R, SIG
// grid 256 (= b(8) x sel(2) x q(16)) x 256
__global__ __launch_bounds__(256) void k1b_reduce(float* __restrict__ ws) {
  const int t = threadIdx.x;
  const int blk = blockIdx.x;
  const int b = blk >> 5, sel = (blk >> 4) & 1, q = blk & 15;
  const float* SB = ws + OFF_STATS + (size_t)b * 64 * PS + (size_t)sel * 4096;
  float* dst = ws + (sel ? OFF_A2R : OFF_A1R) + (size_t)b * 4096;
  const int e = q * 256 + t;
  float s = 0.f;
  #pragma unroll 8
  for (int p = 0; p < 64; ++p) s += SB[(size_t)p * PS + e];
  dst[e] = s;
  if (sel == 0 && q == 0) {
    const float* UB = ws + OFF_STATS + (size_t)b * 64 * PS;
    if (t < 64) {
      float s2 = 0.f;
      #pragma unroll 8
      for (int p = 0; p < 64; ++p) s2 += UB[(size_t)p * PS + 8192 + t];
      ws[OFF_U1R + b * 64 + t] = s2;
    } else if (t < 128) {
      const int i = t - 64;
      float s2 = 0.f;
      #pragma unroll 8
      for (int p = 0; p < 64; ++p) s2 += UB[(size_t)p * PS + 8256 + i];
      ws[OFF_U2R + b * 64 + i] = s2;
    } else if (t == 128) {
      float s1 = 0.f, s2 = 0.f;
      for (int p = 0; p < 64; ++p) {
        s1 += UB[(size_t)p * PS + 8320];
        s2 += UB[(size_t)p * PS + 8321];
      }
      ws[OFF_SIG + b * 2] = s1;
      ws[OFF_SIG + b * 2 + 1] = s2;
    }
  }
}

// ---------------------------------------------------------------------------
// k2p: Td = A1 @ Wv - A2 @ M  [64 x 512 per batch]
//      p1 = Wk^T u1, p2 = Wk^T u2 (h-indexed), q1 = Wv^T u1, g = u2^T M (d-indexed)
// grid 128 (= b(8) x ds(16, 32-wide)) x 256
__global__ __launch_bounds__(256) void k2p_td(const float* __restrict__ Wk,
                                              const float* __restrict__ Wv,
                                              float* __restrict__ ws) {
  __shared__ __align__(16) float A1s[64][66];
  __shared__ __align__(16) float A2s[64][66];
  __shared__ __align__(16) float Wvt[64][36];
  __shared__ __align__(16) float Mt[64][36];
  __shared__ __align__(16) float u1s[64];
  __shared__ __align__(16) float u2s[64];

  const int t = threadIdx.x;
  const int blk = blockIdx.x;
  const int b = blk >> 4;
  const int ds = blk & 15;
  const int d04 = ds * 8;

  const float4* A1R4 = (const float4*)(ws + OFF_A1R + (size_t)b * 4096);
  const float4* A2R4 = (const float4*)(ws + OFF_A2R + (size_t)b * 4096);
  #pragma unroll
  for (int p = 0; p < 4; ++p) {
    const int idx = p * 256 + t;
    const int r = idx >> 4, c0 = (idx & 15) * 4;
    *(float4*)&A1s[r][c0] = A1R4[idx];
    *(float4*)&A2s[r][c0] = A2R4[idx];
  }
  const float4* Wv4 = (const float4*)Wv;
  const float4* M4 = (const float4*)(ws + OFF_M + (size_t)b * 64 * Hn);
  #pragma unroll
  for (int p = 0; p < 2; ++p) {
    const int idx = p * 256 + t;
    const int r = idx >> 3, c4 = idx & 7;
    *(float4*)&Wvt[r][c4 * 4] = Wv4[(size_t)r * 128 + d04 + c4];
    *(float4*)&Mt[r][c4 * 4]  = M4[(size_t)r * 128 + d04 + c4];
  }
  if (t < 16) {
    *(float4*)&u1s[t * 4] = *(const float4*)(ws + OFF_U1R + b * 64 + t * 4);
  } else if (t < 32) {
    const int i = t - 16;
    *(float4*)&u2s[i * 4] = *(const float4*)(ws + OFF_U2R + b * 64 + i * 4);
  }
  __syncthreads();

  const int ig = t >> 3;         // rows i = ig*2, ig*2+1
  const int tj4 = t & 7;
  float4 acc0 = make_float4(0.f, 0.f, 0.f, 0.f);
  float4 acc1 = make_float4(0.f, 0.f, 0.f, 0.f);
  #pragma unroll 8
  for (int j = 0; j < 64; ++j) {
    const float4 wv = *(const float4*)&Wvt[j][tj4 * 4];
    const float4 mv = *(const float4*)&Mt[j][tj4 * 4];
    const float a10 = A1s[ig * 2][j], a20 = A2s[ig * 2][j];
    const float a11 = A1s[ig * 2 + 1][j], a21 = A2s[ig * 2 + 1][j];
    acc0.x += a10 * wv.x - a20 * mv.x; acc0.y += a10 * wv.y - a20 * mv.y;
    acc0.z += a10 * wv.z - a20 * mv.z; acc0.w += a10 * wv.w - a20 * mv.w;
    acc1.x += a11 * wv.x - a21 * mv.x; acc1.y += a11 * wv.y - a21 * mv.y;
    acc1.z += a11 * wv.z - a21 * mv.z; acc1.w += a11 * wv.w - a21 * mv.w;
  }
  float4* Td4 = (float4*)(ws + OFF_TD + (size_t)b * 64 * Hn);
  Td4[(size_t)(ig * 2)     * 128 + d04 + tj4] = acc0;
  Td4[(size_t)(ig * 2 + 1) * 128 + d04 + tj4] = acc1;

  // rank-1 vectors for this 32-wide strip
  if (t < 32) {
    const int d = ds * 32 + t;
    float q1 = 0.f, g = 0.f;
    #pragma unroll 8
    for (int i = 0; i < 64; ++i) {
      q1 += u1s[i] * Wvt[i][t];
      g  += u2s[i] * Mt[i][t];
    }
    ws[OFF_Q1 + (size_t)b * Hn + d] = q1;
    ws[OFF_GV + (size_t)b * Hn + d] = g;
  } else if (t < 64) {
    const int h = ds * 32 + (t - 32);
    float p1 = 0.f, p2 = 0.f;
    #pragma unroll 8
    for (int i = 0; i < 64; ++i) {
      const float wv = Wk[(size_t)i * Hn + h];
      p1 += wv * u1s[i];
      p2 += wv * u2s[i];
    }
    ws[OFF_P1 + (size_t)b * Hn + h] = p1;
    ws[OFF_P2 + (size_t)b * Hn + h] = p2;
  }
}

// ---------------------------------------------------------------------------
// k4: out = C + Wk^T Td + (p1 + sig1*bk) (x) bv + bk (x) (q1 - g - sig2*c1) - p2 (x) c1
// grid 256 (= b(8) x hstrip(8, 64-wide) x dstrip(4, 128-wide)) x 256
__global__ __launch_bounds__(256) void k4_out(const float* __restrict__ C,
                                              const float* __restrict__ Wk,
                                              const float* __restrict__ bk,
                                              const float* __restrict__ bv,
                                              const float* __restrict__ ws,
                                              float* __restrict__ out) {
  __shared__ __align__(16) float Tds[64][132];
  __shared__ __align__(16) float Wks[64][68];
  __shared__ float phs[64], bks[64], p2s[64];
  __shared__ float bvs[128], terms[128], c1s[128];

  const int t = threadIdx.x;
  const int blk = blockIdx.x;
  const int b = blk >> 5;
  const int hs0 = ((blk >> 2) & 7) * 64;
  const int d04 = (blk & 3) * 32;               // float4 offset of 128-wide d strip
  const float sg1 = ws[OFF_SIG + b * 2];
  const float sg2 = ws[OFF_SIG + b * 2 + 1];

  const float4* TdG4 = (const float4*)(ws + OFF_TD + (size_t)b * 64 * Hn);
  #pragma unroll
  for (int p = 0; p < 8; ++p) {
    const int idx = p * 256 + t;                // 2048 float4
    const int r = idx >> 5, c4 = idx & 31;
    *(float4*)&Tds[r][c4 * 4] = TdG4[(size_t)r * 128 + d04 + c4];
  }
  const float4* Wk4 = (const float4*)Wk;
  #pragma unroll
  for (int p = 0; p < 4; ++p) {
    const int idx = p * 256 + t;                // 1024 float4
    const int r = idx >> 4, c4 = idx & 15;
    *(float4*)&Wks[r][c4 * 4] = Wk4[(size_t)r * 128 + (hs0 >> 2) + c4];
  }
  if (t < 64) {
    const int h = hs0 + t;
    const float bkv = bk[h];
    bks[t] = bkv;
    phs[t] = ws[OFF_P1 + (size_t)b * Hn + h] + sg1 * bkv;
    p2s[t] = ws[OFF_P2 + (size_t)b * Hn + h];
  } else if (t < 192) {
    const int dd = t - 64;
    const int d = d04 * 4 + dd;
    const float c1 = ws[OFF_C1 + (size_t)b * Hn + d];
    c1s[dd] = c1;
    bvs[dd] = bv[d];
    terms[dd] = ws[OFF_Q1 + (size_t)b * Hn + d] - ws[OFF_GV + (size_t)b * Hn + d] - sg2 * c1;
  }
  __syncthreads();

  const int ti = t >> 5;   // rows hh = ti*8 .. +8
  const int tj4 = t & 31;  // d float4 within strip
  float4 acc[8];
  #pragma unroll
  for (int a = 0; a < 8; ++a) acc[a] = make_float4(0.f, 0.f, 0.f, 0.f);
  for (int j = 0; j < 64; ++j) {
    const float4 td4 = *(const float4*)&Tds[j][tj4 * 4];
    #pragma unroll
    for (int a = 0; a < 8; ++a) {
      const float wv = Wks[j][ti * 8 + a];
      acc[a].x += wv * td4.x; acc[a].y += wv * td4.y;
      acc[a].z += wv * td4.z; acc[a].w += wv * td4.w;
    }
  }

  const float4* C4b = (const float4*)(C + (size_t)b * Hn * Hn);
  float4* out4 = (float4*)(out + (size_t)b * Hn * Hn);
  const float4 bv4 = *(const float4*)&bvs[tj4 * 4];
  const float4 tm4 = *(const float4*)&terms[tj4 * 4];
  const float4 c14 = *(const float4*)&c1s[tj4 * 4];
  #pragma unroll
  for (int a = 0; a < 8; ++a) {
    const int hh = ti * 8 + a;
    const int h = hs0 + hh;
    const float4 c = C4b[(size_t)h * 128 + d04 + tj4];
    const float ph = phs[hh], bkh = bks[hh], p2h = p2s[hh];
    float4 o;
    o.x = c.x + acc[a].x + ph * bv4.x + bkh * tm4.x - p2h * c14.x;
    o.y = c.y + acc[a].y + ph * bv4.y + bkh * tm4.y - p2h * c14.y;
    o.z = c.z + acc[a].z + ph * bv4.z + bkh * tm4.z - p2h * c14.z;
    o.w = c.w + acc[a].w + ph * bv4.w + bkh * tm4.w - p2h * c14.w;
    out4[(size_t)h * 128 + d04 + tj4] = o;
  }
}

// ---------------------------------------------------------------------------
extern "C" void kernel_launch(void* const* d_in, const int* in_sizes, int n_in,
                              void* d_out, int out_size, void* d_ws, size_t ws_size,
                              hipStream_t stream) {
  const float* hs = (const float*)d_in[0];
  const float* C  = (const float*)d_in[1];
  const float* Wk = (const float*)d_in[2];
  const float* bk = (const float*)d_in[3];
  const float* Wv = (const float*)d_in[4];
  const float* bv = (const float*)d_in[5];
  float* out = (float*)d_out;
  float* ws = (float*)d_ws;
  (void)in_sizes; (void)n_in; (void)out_size; (void)ws_size;

  hipLaunchKernelGGL(kA_pre,     dim3(145), dim3(256), 0, stream, Wk, bk, C, ws);
  hipLaunchKernelGGL(k1_stats,   dim3(512), dim3(256), 0, stream, hs, ws);
  hipLaunchKernelGGL(k1b_reduce, dim3(256), dim3(256), 0, stream, ws);
  hipLaunchKernelGGL(k2p_td,     dim3(128), dim3(256), 0, stream, Wk, Wv, ws);
  hipLaunchKernelGGL(k4_out,     dim3(256), dim3(256), 0, stream, C, Wk, bk, bv, ws, out);
}

// Round 4
// 83.742 us; speedup vs baseline: 1.2036x; 1.2036x over previous
//
#include <hip/hip_runtime.h>
#include <math.h>

namespace {
constexpr int Bn = 8;
constexpr int Ln = 8192;
constexpr int Rn = 64;
constexpr int Hn = 512;
constexpr int LT = 128;
constexpr int NSEG = Ln / LT;            // 64 segments per batch
constexpr int NK1 = Bn * NSEG;           // 512 k1 blocks
constexpr int NHC = 4;                   // M h-chunks (128 h each)

// workspace float offsets
constexpr size_t PS        = 8352;       // per-k1-block partial stride
constexpr size_t OFF_G     = 0;                                   // 64x64
constexpr size_t OFF_W     = 4096;                                // 64
constexpr size_t OFF_BB    = 4160;                                // 1 (+pad)
constexpr size_t OFF_STATS = 4224;                                // NK1 * PS
constexpr size_t OFF_A1R   = OFF_STATS + (size_t)NK1 * PS;        // B*4096
constexpr size_t OFF_A2R   = OFF_A1R + (size_t)Bn * 4096;         // B*4096
constexpr size_t OFF_U1R   = OFF_A2R + (size_t)Bn * 4096;         // B*64
constexpr size_t OFF_U2R   = OFF_U1R + (size_t)Bn * 64;           // B*64
constexpr size_t OFF_SIG   = OFF_U2R + (size_t)Bn * 64;           // B*2 (pad 64)
constexpr size_t OFF_MP    = OFF_SIG + 64;                        // B*NHC*64*H (M h-partials)
constexpr size_t OFF_C1P   = OFF_MP + (size_t)Bn * NHC * 64 * Hn; // B*NHC*H
constexpr size_t OFF_TD    = OFF_C1P + (size_t)Bn * NHC * Hn;     // B*64*H
constexpr size_t OFF_P1    = OFF_TD + (size_t)Bn * 64 * Hn;       // B*H
constexpr size_t OFF_P2    = OFF_P1 + (size_t)Bn * Hn;            // B*H
constexpr size_t OFF_Q1    = OFF_P2 + (size_t)Bn * Hn;            // B*H
constexpr size_t OFF_GV    = OFF_Q1 + (size_t)Bn * Hn;            // B*H     (g = u2^T M)
}

// ---------------------------------------------------------------------------
// kA: blocks 0..63  : G[i][j] = Wk_i . Wk_j  (block = row i, 4 lanes per dot)
//     block 64      : w = Wk*bk, bb = bk.bk
//     blocks 65..576: M h-partials: MP[b][hc] = Wk[:, hc*128:+128] @ C[chunk, dstrip]
//                     + c1 partials C1P[b][hc] = bk_chunk^T C_chunk
// grid 577 x 256
__global__ __launch_bounds__(256) void kA_pre(const float* __restrict__ Wk,
                                              const float* __restrict__ bk,
                                              const float* __restrict__ C,
                                              float* __restrict__ ws) {
  const int t = threadIdx.x;
  const int blk = blockIdx.x;

  if (blk < 64) {
    // G row blk
    const int j = t >> 2, kq = t & 3;
    const float4* a4 = (const float4*)(Wk + (size_t)blk * Hn) + kq * 32;
    const float4* b4 = (const float4*)(Wk + (size_t)j * Hn) + kq * 32;
    float s0 = 0.f, s1 = 0.f, s2 = 0.f, s3 = 0.f;
    #pragma unroll 8
    for (int h = 0; h < 32; ++h) {
      const float4 x = a4[h], y = b4[h];
      s0 += x.x * y.x; s1 += x.y * y.y; s2 += x.z * y.z; s3 += x.w * y.w;
    }
    float s = (s0 + s1) + (s2 + s3);
    s += __shfl_down(s, 2, 4);
    s += __shfl_down(s, 1, 4);
    if (kq == 0) ws[OFF_G + blk * 64 + j] = s;
    return;
  }
  if (blk == 64) {
    const int i = t >> 2, kq = t & 3;
    const float4* a4 = (const float4*)(Wk + (size_t)i * Hn) + kq * 32;
    const float4* b4 = (const float4*)bk + kq * 32;
    float s0 = 0.f, s1 = 0.f, s2 = 0.f, s3 = 0.f;
    #pragma unroll 8
    for (int h = 0; h < 32; ++h) {
      const float4 x = a4[h], y = b4[h];
      s0 += x.x * y.x; s1 += x.y * y.y; s2 += x.z * y.z; s3 += x.w * y.w;
    }
    float s = (s0 + s1) + (s2 + s3);
    s += __shfl_down(s, 2, 4);
    s += __shfl_down(s, 1, 4);
    if (kq == 0) ws[OFF_W + i] = s;
    if (t < 4) {
      const float4* b4b = (const float4*)bk + t * 32;
      float q0 = 0.f, q1 = 0.f, q2 = 0.f, q3 = 0.f;
      #pragma unroll 8
      for (int h = 0; h < 32; ++h) {
        const float4 y = b4b[h];
        q0 += y.x * y.x; q1 += y.y * y.y; q2 += y.z * y.z; q3 += y.w * y.w;
      }
      float q = (q0 + q1) + (q2 + q3);
      q += __shfl_down(q, 2, 4);
      q += __shfl_down(q, 1, 4);
      if (t == 0) ws[OFF_BB] = q;
    }
    return;
  }

  // ---- M / c1 partials ----
  __shared__ __align__(16) float Wks[64][132];  // [i][h within 128-chunk]
  __shared__ __align__(16) float Cs[128][36];   // [h within chunk][d within strip]
  __shared__ __align__(16) float bks[128];

  const int m = blk - 65;
  const int b = m >> 6;
  const int rem = m & 63;
  const int hc = rem >> 4;
  const int ds = rem & 15;
  const int h0 = hc * 128;
  const int d04 = ds * 8;                       // float4 offset of 32-wide strip

  const float4* Wk4 = (const float4*)Wk;
  const float4* C4b = (const float4*)(C + (size_t)b * Hn * Hn);
  #pragma unroll
  for (int p = 0; p < 8; ++p) {
    const int idx = p * 256 + t;                // 2048 float4 (64 x 32)
    const int r = idx >> 5, c4 = idx & 31;
    *(float4*)&Wks[r][c4 * 4] = Wk4[(size_t)r * 128 + (h0 >> 2) + c4];
  }
  #pragma unroll
  for (int p = 0; p < 4; ++p) {
    const int idx = p * 256 + t;                // 1024 float4 (128 x 8)
    const int r = idx >> 3, c4 = idx & 7;
    *(float4*)&Cs[r][c4 * 4] = C4b[(size_t)(h0 + r) * 128 + d04 + c4];
  }
  if (t < 32) *(float4*)&bks[t * 4] = *(const float4*)&bk[h0 + t * 4];
  __syncthreads();

  const int ig = t >> 3;                        // rows 2ig, 2ig+1
  const int tj4 = t & 7;
  float4 acc0 = make_float4(0.f, 0.f, 0.f, 0.f);
  float4 acc1 = make_float4(0.f, 0.f, 0.f, 0.f);
  float4 c1a  = make_float4(0.f, 0.f, 0.f, 0.f);
  #pragma unroll 8
  for (int hh = 0; hh < 128; ++hh) {
    const float4 cv = *(const float4*)&Cs[hh][tj4 * 4];
    const float w0 = Wks[ig * 2][hh];
    const float w1 = Wks[ig * 2 + 1][hh];
    acc0.x += w0 * cv.x; acc0.y += w0 * cv.y; acc0.z += w0 * cv.z; acc0.w += w0 * cv.w;
    acc1.x += w1 * cv.x; acc1.y += w1 * cv.y; acc1.z += w1 * cv.z; acc1.w += w1 * cv.w;
    if (ig == 0) {
      const float bkv = bks[hh];
      c1a.x += bkv * cv.x; c1a.y += bkv * cv.y; c1a.z += bkv * cv.z; c1a.w += bkv * cv.w;
    }
  }

  float4* MP4 = (float4*)(ws + OFF_MP);
  const size_t base = (size_t)(b * NHC + hc) * 64;
  MP4[(base + ig * 2)     * 128 + d04 + tj4] = acc0;
  MP4[(base + ig * 2 + 1) * 128 + d04 + tj4] = acc1;
  if (ig == 0) {
    float4* c14 = (float4*)(ws + OFF_C1P);
    c14[(size_t)(b * NHC + hc) * 128 + d04 + tj4] = c1a;
  }
}

// ---------------------------------------------------------------------------
// k1: per 128-row tile: row norms via x*G*x + 2x.w + bb, then accumulate
//     A1 = X^T D X, A2 = X^T D^2 X, u1, u2, sig partials.
// grid 512 (= 8 b x 64 seg) x 256
__global__ __launch_bounds__(256) void k1_stats(const float* __restrict__ hs,
                                                float* __restrict__ ws) {
  __shared__ __align__(16) float XT[64][132];   // [r][l], padded
  __shared__ __align__(16) float Gs[64][64];
  __shared__ __align__(16) float wsh[64];
  __shared__ __align__(16) float n2p[8][LT];
  __shared__ __align__(16) float d1s[LT];
  __shared__ __align__(16) float d2s[LT];

  const int t = threadIdx.x;
  const int blk = blockIdx.x;
  const int b = blk >> 6;
  const int seg = blk & 63;

  for (int k = 0; k < 16; ++k) {
    int e = k * 256 + t;
    (&Gs[0][0])[e] = ws[OFF_G + e];
  }
  if (t < 64) wsh[t] = ws[OFF_W + t];
  const float bb = ws[OFF_BB];

  // stage X transposed: XT[r][l]
  {
    const float4* src = (const float4*)(hs + ((size_t)b * Ln + (size_t)seg * LT) * Rn);
    #pragma unroll
    for (int k = 0; k < 8; ++k) {
      int f = k * 256 + t;
      float4 v = src[f];
      int l = f >> 4, j0 = (f & 15) << 2;
      XT[j0 + 0][l] = v.x; XT[j0 + 1][l] = v.y; XT[j0 + 2][l] = v.z; XT[j0 + 3][l] = v.w;
    }
  }
  __syncthreads();

  // phase A: Y[i][l] = sum_k G[i][k]*XT[k][l]; n2 partials
  {
    const int i0 = (t & 7) * 8;
    const int la = (t >> 3) * 4;
    float acc[8][4] = {};
    for (int k = 0; k < 64; ++k) {
      const float4 g0 = *(const float4*)&Gs[k][i0];
      const float4 g1 = *(const float4*)&Gs[k][i0 + 4];
      const float4 xv = *(const float4*)&XT[k][la];
      const float ga[8] = {g0.x, g0.y, g0.z, g0.w, g1.x, g1.y, g1.z, g1.w};
      const float xa[4] = {xv.x, xv.y, xv.z, xv.w};
      #pragma unroll
      for (int a = 0; a < 8; ++a)
        #pragma unroll
        for (int lv = 0; lv < 4; ++lv)
          acc[a][lv] += ga[a] * xa[lv];
    }
    #pragma unroll
    for (int lv = 0; lv < 4; ++lv) {
      float s = 0.f;
      #pragma unroll
      for (int a = 0; a < 8; ++a)
        s += XT[i0 + a][la + lv] * (acc[a][lv] + 2.0f * wsh[i0 + a]);
      n2p[t & 7][la + lv] = s;
    }
  }
  __syncthreads();
  if (t < LT) {
    float n2 = bb;
    #pragma unroll
    for (int p = 0; p < 8; ++p) n2 += n2p[p][t];
    n2 = fmaxf(n2, 0.0f);
    const float d1 = 1.0f / fmaxf(sqrtf(n2), 1e-12f);
    d1s[t] = d1;
    d2s[t] = d1 * d1;
  }
  __syncthreads();

  float sg1 = 0.f, sg2 = 0.f;
  if (t < 64) {
    float a1 = d1s[t] + d1s[t + 64];
    float a2 = d2s[t] + d2s[t + 64];
    #pragma unroll
    for (int off = 32; off > 0; off >>= 1) {
      a1 += __shfl_down(a1, off, 64);
      a2 += __shfl_down(a2, off, 64);
    }
    sg1 = a1; sg2 = a2;
  }

  // phase B: A1/A2 4x4 per-thread accumulation over the tile
  const int bi0 = (t >> 4) * 4;
  const int bj0 = (t & 15) * 4;
  float A1a[4][4] = {}, A2a[4][4] = {};
  float u1a[4] = {0.f, 0.f, 0.f, 0.f}, u2a[4] = {0.f, 0.f, 0.f, 0.f};
  for (int l4 = 0; l4 < LT; l4 += 4) {
    const float4 q1 = *(const float4*)&d1s[l4];
    const float4 q2 = *(const float4*)&d2s[l4];
    const float d1v[4] = {q1.x, q1.y, q1.z, q1.w};
    const float d2v[4] = {q2.x, q2.y, q2.z, q2.w};
    float e1[4][4], e2[4][4], xj[4][4];
    #pragma unroll
    for (int a = 0; a < 4; ++a) {
      const float4 xv = *(const float4*)&XT[bi0 + a][l4];
      const float xa[4] = {xv.x, xv.y, xv.z, xv.w};
      #pragma unroll
      for (int lv = 0; lv < 4; ++lv) {
        e1[a][lv] = d1v[lv] * xa[lv];
        e2[a][lv] = d2v[lv] * xa[lv];
      }
    }
    #pragma unroll
    for (int bq = 0; bq < 4; ++bq) {
      const float4 xv = *(const float4*)&XT[bj0 + bq][l4];
      xj[bq][0] = xv.x; xj[bq][1] = xv.y; xj[bq][2] = xv.z; xj[bq][3] = xv.w;
    }
    #pragma unroll
    for (int a = 0; a < 4; ++a)
      #pragma unroll
      for (int bq = 0; bq < 4; ++bq) {
        float s1 = A1a[a][bq], s2 = A2a[a][bq];
        #pragma unroll
        for (int lv = 0; lv < 4; ++lv) {
          s1 += e1[a][lv] * xj[bq][lv];
          s2 += e2[a][lv] * xj[bq][lv];
        }
        A1a[a][bq] = s1; A2a[a][bq] = s2;
      }
    if (bj0 == 0) {
      #pragma unroll
      for (int a = 0; a < 4; ++a)
        #pragma unroll
        for (int lv = 0; lv < 4; ++lv) {
          u1a[a] += e1[a][lv];
          u2a[a] += e2[a][lv];
        }
    }
  }

  float* P = ws + OFF_STATS + (size_t)blk * PS;
  #pragma unroll
  for (int a = 0; a < 4; ++a)
    #pragma unroll
    for (int bq = 0; bq < 4; ++bq) {
      P[(bi0 + a) * 64 + bj0 + bq] = A1a[a][bq];
      P[4096 + (bi0 + a) * 64 + bj0 + bq] = A2a[a][bq];
    }
  if (bj0 == 0) {
    #pragma unroll
    for (int a = 0; a < 4; ++a) {
      P[8192 + bi0 + a] = u1a[a];
      P[8256 + bi0 + a] = u2a[a];
    }
  }
  if (t == 0) { P[8320] = sg1; P[8321] = sg2; }
}

// ---------------------------------------------------------------------------
// k1b: reduce 64 partials per batch -> A1R, A2R, U1R, U2R, SIG
// grid 256 (= b(8) x sel(2) x q(16)) x 256
__global__ __launch_bounds__(256) void k1b_reduce(float* __restrict__ ws) {
  const int t = threadIdx.x;
  const int blk = blockIdx.x;
  const int b = blk >> 5, sel = (blk >> 4) & 1, q = blk & 15;
  const float* SB = ws + OFF_STATS + (size_t)b * 64 * PS + (size_t)sel * 4096;
  float* dst = ws + (sel ? OFF_A2R : OFF_A1R) + (size_t)b * 4096;
  const int e = q * 256 + t;
  float s = 0.f;
  #pragma unroll 8
  for (int p = 0; p < 64; ++p) s += SB[(size_t)p * PS + e];
  dst[e] = s;
  if (sel == 0 && q == 0) {
    const float* UB = ws + OFF_STATS + (size_t)b * 64 * PS;
    if (t < 64) {
      float s2 = 0.f;
      #pragma unroll 8
      for (int p = 0; p < 64; ++p) s2 += UB[(size_t)p * PS + 8192 + t];
      ws[OFF_U1R + b * 64 + t] = s2;
    } else if (t < 128) {
      const int i = t - 64;
      float s2 = 0.f;
      #pragma unroll 8
      for (int p = 0; p < 64; ++p) s2 += UB[(size_t)p * PS + 8256 + i];
      ws[OFF_U2R + b * 64 + i] = s2;
    } else if (t == 128) {
      float s1 = 0.f, s2 = 0.f;
      for (int p = 0; p < 64; ++p) {
        s1 += UB[(size_t)p * PS + 8320];
        s2 += UB[(size_t)p * PS + 8321];
      }
      ws[OFF_SIG + b * 2] = s1;
      ws[OFF_SIG + b * 2 + 1] = s2;
    }
  }
}

// ---------------------------------------------------------------------------
// k2p: Td = A1 @ Wv - A2 @ M  [64 x 512 per batch]   (M = sum of 4 h-partials)
//      p1 = Wk^T u1, p2 = Wk^T u2 (h-indexed), q1 = Wv^T u1, g = u2^T M (d-indexed)
// grid 128 (= b(8) x ds(16, 32-wide)) x 256
__global__ __launch_bounds__(256) void k2p_td(const float* __restrict__ Wk,
                                              const float* __restrict__ Wv,
                                              float* __restrict__ ws) {
  __shared__ __align__(16) float A1s[64][66];
  __shared__ __align__(16) float A2s[64][66];
  __shared__ __align__(16) float Wvt[64][36];
  __shared__ __align__(16) float Mt[64][36];
  __shared__ __align__(16) float u1s[64];
  __shared__ __align__(16) float u2s[64];

  const int t = threadIdx.x;
  const int blk = blockIdx.x;
  const int b = blk >> 4;
  const int ds = blk & 15;
  const int d04 = ds * 8;

  const float4* A1R4 = (const float4*)(ws + OFF_A1R + (size_t)b * 4096);
  const float4* A2R4 = (const float4*)(ws + OFF_A2R + (size_t)b * 4096);
  #pragma unroll
  for (int p = 0; p < 4; ++p) {
    const int idx = p * 256 + t;
    const int r = idx >> 4, c0 = (idx & 15) * 4;
    *(float4*)&A1s[r][c0] = A1R4[idx];
    *(float4*)&A2s[r][c0] = A2R4[idx];
  }
  const float4* Wv4 = (const float4*)Wv;
  const float4* MP4 = (const float4*)(ws + OFF_MP);
  #pragma unroll
  for (int p = 0; p < 2; ++p) {
    const int idx = p * 256 + t;
    const int r = idx >> 3, c4 = idx & 7;
    *(float4*)&Wvt[r][c4 * 4] = Wv4[(size_t)r * 128 + d04 + c4];
    float4 m = MP4[((size_t)(b * NHC + 0) * 64 + r) * 128 + d04 + c4];
    #pragma unroll
    for (int q = 1; q < NHC; ++q) {
      const float4 mq = MP4[((size_t)(b * NHC + q) * 64 + r) * 128 + d04 + c4];
      m.x += mq.x; m.y += mq.y; m.z += mq.z; m.w += mq.w;
    }
    *(float4*)&Mt[r][c4 * 4] = m;
  }
  if (t < 16) {
    *(float4*)&u1s[t * 4] = *(const float4*)(ws + OFF_U1R + b * 64 + t * 4);
  } else if (t < 32) {
    const int i = t - 16;
    *(float4*)&u2s[i * 4] = *(const float4*)(ws + OFF_U2R + b * 64 + i * 4);
  }
  __syncthreads();

  const int ig = t >> 3;         // rows i = ig*2, ig*2+1
  const int tj4 = t & 7;
  float4 acc0 = make_float4(0.f, 0.f, 0.f, 0.f);
  float4 acc1 = make_float4(0.f, 0.f, 0.f, 0.f);
  #pragma unroll 8
  for (int j = 0; j < 64; ++j) {
    const float4 wv = *(const float4*)&Wvt[j][tj4 * 4];
    const float4 mv = *(const float4*)&Mt[j][tj4 * 4];
    const float a10 = A1s[ig * 2][j], a20 = A2s[ig * 2][j];
    const float a11 = A1s[ig * 2 + 1][j], a21 = A2s[ig * 2 + 1][j];
    acc0.x += a10 * wv.x - a20 * mv.x; acc0.y += a10 * wv.y - a20 * mv.y;
    acc0.z += a10 * wv.z - a20 * mv.z; acc0.w += a10 * wv.w - a20 * mv.w;
    acc1.x += a11 * wv.x - a21 * mv.x; acc1.y += a11 * wv.y - a21 * mv.y;
    acc1.z += a11 * wv.z - a21 * mv.z; acc1.w += a11 * wv.w - a21 * mv.w;
  }
  float4* Td4 = (float4*)(ws + OFF_TD + (size_t)b * 64 * Hn);
  Td4[(size_t)(ig * 2)     * 128 + d04 + tj4] = acc0;
  Td4[(size_t)(ig * 2 + 1) * 128 + d04 + tj4] = acc1;

  // rank-1 vectors for this 32-wide strip
  if (t < 32) {
    const int d = ds * 32 + t;
    float q1 = 0.f, g = 0.f;
    #pragma unroll 8
    for (int i = 0; i < 64; ++i) {
      q1 += u1s[i] * Wvt[i][t];
      g  += u2s[i] * Mt[i][t];
    }
    ws[OFF_Q1 + (size_t)b * Hn + d] = q1;
    ws[OFF_GV + (size_t)b * Hn + d] = g;
  } else if (t < 64) {
    const int h = ds * 32 + (t - 32);
    float p1 = 0.f, p2 = 0.f;
    #pragma unroll 8
    for (int i = 0; i < 64; ++i) {
      const float wv = Wk[(size_t)i * Hn + h];
      p1 += wv * u1s[i];
      p2 += wv * u2s[i];
    }
    ws[OFF_P1 + (size_t)b * Hn + h] = p1;
    ws[OFF_P2 + (size_t)b * Hn + h] = p2;
  }
}

// ---------------------------------------------------------------------------
// k4: out = C + Wk^T Td + (p1 + sig1*bk) (x) bv + bk (x) (q1 - g - sig2*c1) - p2 (x) c1
// grid 256 (= b(8) x hstrip(8, 64-wide) x dstrip(4, 128-wide)) x 256
__global__ __launch_bounds__(256) void k4_out(const float* __restrict__ C,
                                              const float* __restrict__ Wk,
                                              const float* __restrict__ bk,
                                              const float* __restrict__ bv,
                                              const float* __restrict__ ws,
                                              float* __restrict__ out) {
  __shared__ __align__(16) float Tds[64][132];
  __shared__ __align__(16) float Wks[64][68];
  __shared__ float phs[64], bks[64], p2s[64];
  __shared__ float bvs[128], terms[128], c1s[128];

  const int t = threadIdx.x;
  const int blk = blockIdx.x;
  const int b = blk >> 5;
  const int hs0 = ((blk >> 2) & 7) * 64;
  const int d04 = (blk & 3) * 32;               // float4 offset of 128-wide d strip
  const float sg1 = ws[OFF_SIG + b * 2];
  const float sg2 = ws[OFF_SIG + b * 2 + 1];

  const float4* TdG4 = (const float4*)(ws + OFF_TD + (size_t)b * 64 * Hn);
  #pragma unroll
  for (int p = 0; p < 8; ++p) {
    const int idx = p * 256 + t;                // 2048 float4
    const int r = idx >> 5, c4 = idx & 31;
    *(float4*)&Tds[r][c4 * 4] = TdG4[(size_t)r * 128 + d04 + c4];
  }
  const float4* Wk4 = (const float4*)Wk;
  #pragma unroll
  for (int p = 0; p < 4; ++p) {
    const int idx = p * 256 + t;                // 1024 float4
    const int r = idx >> 4, c4 = idx & 15;
    *(float4*)&Wks[r][c4 * 4] = Wk4[(size_t)r * 128 + (hs0 >> 2) + c4];
  }
  if (t < 64) {
    const int h = hs0 + t;
    const float bkv = bk[h];
    bks[t] = bkv;
    phs[t] = ws[OFF_P1 + (size_t)b * Hn + h] + sg1 * bkv;
    p2s[t] = ws[OFF_P2 + (size_t)b * Hn + h];
  } else if (t < 192) {
    const int dd = t - 64;
    const int d = d04 * 4 + dd;
    float c1 = 0.f;
    #pragma unroll
    for (int q = 0; q < NHC; ++q)
      c1 += ws[OFF_C1P + (size_t)(b * NHC + q) * Hn + d];
    c1s[dd] = c1;
    bvs[dd] = bv[d];
    terms[dd] = ws[OFF_Q1 + (size_t)b * Hn + d] - ws[OFF_GV + (size_t)b * Hn + d] - sg2 * c1;
  }
  __syncthreads();

  const int ti = t >> 5;   // rows hh = ti*8 .. +8
  const int tj4 = t & 31;  // d float4 within strip
  float4 acc[8];
  #pragma unroll
  for (int a = 0; a < 8; ++a) acc[a] = make_float4(0.f, 0.f, 0.f, 0.f);
  for (int j = 0; j < 64; ++j) {
    const float4 td4 = *(const float4*)&Tds[j][tj4 * 4];
    #pragma unroll
    for (int a = 0; a < 8; ++a) {
      const float wv = Wks[j][ti * 8 + a];
      acc[a].x += wv * td4.x; acc[a].y += wv * td4.y;
      acc[a].z += wv * td4.z; acc[a].w += wv * td4.w;
    }
  }

  const float4* C4b = (const float4*)(C + (size_t)b * Hn * Hn);
  float4* out4 = (float4*)(out + (size_t)b * Hn * Hn);
  const float4 bv4 = *(const float4*)&bvs[tj4 * 4];
  const float4 tm4 = *(const float4*)&terms[tj4 * 4];
  const float4 c14 = *(const float4*)&c1s[tj4 * 4];
  #pragma unroll
  for (int a = 0; a < 8; ++a) {
    const int hh = ti * 8 + a;
    const int h = hs0 + hh;
    const float4 c = C4b[(size_t)h * 128 + d04 + tj4];
    const float ph = phs[hh], bkh = bks[hh], p2h = p2s[hh];
    float4 o;
    o.x = c.x + acc[a].x + ph * bv4.x + bkh * tm4.x - p2h * c14.x;
    o.y = c.y + acc[a].y + ph * bv4.y + bkh * tm4.y - p2h * c14.y;
    o.z = c.z + acc[a].z + ph * bv4.z + bkh * tm4.z - p2h * c14.z;
    o.w = c.w + acc[a].w + ph * bv4.w + bkh * tm4.w - p2h * c14.w;
    out4[(size_t)h * 128 + d04 + tj4] = o;
  }
}

// ---------------------------------------------------------------------------
extern "C" void kernel_launch(void* const* d_in, const int* in_sizes, int n_in,
                              void* d_out, int out_size, void* d_ws, size_t ws_size,
                              hipStream_t stream) {
  const float* hs = (const float*)d_in[0];
  const float* C  = (const float*)d_in[1];
  const float* Wk = (const float*)d_in[2];
  const float* bk = (const float*)d_in[3];
  const float* Wv = (const float*)d_in[4];
  const float* bv = (const float*)d_in[5];
  float* out = (float*)d_out;
  float* ws = (float*)d_ws;
  (void)in_sizes; (void)n_in; (void)out_size; (void)ws_size;

  hipLaunchKernelGGL(kA_pre,     dim3(577), dim3(256), 0, stream, Wk, bk, C, ws);
  hipLaunchKernelGGL(k1_stats,   dim3(512), dim3(256), 0, stream, hs, ws);
  hipLaunchKernelGGL(k1b_reduce, dim3(256), dim3(256), 0, stream, ws);
  hipLaunchKernelGGL(k2p_td,     dim3(128), dim3(256), 0, stream, Wk, Wv, ws);
  hipLaunchKernelGGL(k4_out,     dim3(256), dim3(256), 0, stream, C, Wk, bk, bv, ws, out);
}